// Round 1
// baseline (380.486 us; speedup 1.0000x reference)
//
#include <hip/hip_runtime.h>

#define TD 256   // threads per block everywhere

// ---------------- degree / CSR build ----------------

__global__ void k_init_deg(int* __restrict__ deg, int n) {
    int i = blockIdx.x * TD + threadIdx.x;
    if (i < n) deg[i] = 0;
}

__global__ void k_count(const int* __restrict__ dst, int e, int* __restrict__ deg) {
    int i = blockIdx.x * TD + threadIdx.x;
    if (i < e) atomicAdd(&deg[dst[i]], 1);
}

// per-block sums of deg
__global__ void k_scanA(const int* __restrict__ deg, int n, int* __restrict__ bsum) {
    __shared__ int s[TD];
    int t = threadIdx.x;
    int i = blockIdx.x * TD + t;
    s[t] = (i < n) ? deg[i] : 0;
    __syncthreads();
    for (int off = TD / 2; off > 0; off >>= 1) {
        if (t < off) s[t] += s[t + off];
        __syncthreads();
    }
    if (t == 0) bsum[blockIdx.x] = s[0];
}

// exclusive scan of block sums (nb <= 256), in place
__global__ void k_scanB(int* __restrict__ bsum, int nb) {
    __shared__ int s[TD];
    int t = threadIdx.x;
    int v = (t < nb) ? bsum[t] : 0;
    s[t] = v;
    __syncthreads();
    for (int off = 1; off < TD; off <<= 1) {
        int u = (t >= off) ? s[t - off] : 0;
        __syncthreads();
        s[t] += u;
        __syncthreads();
    }
    if (t < nb) bsum[t] = s[t] - v;   // exclusive
}

// per-block exclusive scan + block offset -> rowStart, cursor; also dinv = rsqrt(deg+1)
__global__ void k_scanC(const int* __restrict__ deg, int n, const int* __restrict__ bsum,
                        int* __restrict__ rowStart, int* __restrict__ cursor,
                        float* __restrict__ dinv) {
    __shared__ int s[TD];
    int t = threadIdx.x;
    int i = blockIdx.x * TD + t;
    int v = (i < n) ? deg[i] : 0;
    s[t] = v;
    __syncthreads();
    for (int off = 1; off < TD; off <<= 1) {
        int u = (t >= off) ? s[t - off] : 0;
        __syncthreads();
        s[t] += u;
        __syncthreads();
    }
    if (i < n) {
        int rs = bsum[blockIdx.x] + s[t] - v;
        rowStart[i] = rs;
        cursor[i]   = rs;
        dinv[i]     = rsqrtf((float)(v + 1));   // +1 self-loop
    }
}

__global__ void k_fill(const int* __restrict__ src, const int* __restrict__ dst, int e,
                       int* __restrict__ cursor, int* __restrict__ csr) {
    int i = blockIdx.x * TD + threadIdx.x;
    if (i < e) {
        int d = dst[i];
        int slot = atomicAdd(&cursor[d], 1);
        csr[slot] = src[i];
    }
}

// ---------------- xws = (x @ Wg) * dinv[row] ----------------
// 32 rows x 128 cols per block, K chunked by 64 (LDS: 32KB + 8KB)
__global__ __launch_bounds__(256) void k_xw(const float* __restrict__ x,
                                            const float* __restrict__ W,
                                            const float* __restrict__ dinv,
                                            float* __restrict__ xws, int n) {
    __shared__ float sW[64][128];   // [k][c] chunk
    __shared__ float sX[64][32];    // [k][r] transposed chunk
    int t = threadIdx.x;
    int row0 = blockIdx.x * 32;
    int rt = t >> 5;   // 0..7 -> rows rt*4..+3
    int ct = t & 31;   // 0..31 -> cols ct*4..+3
    float acc[4][4] = {};
    for (int kc = 0; kc < 128; kc += 64) {
        for (int i = t; i < 2048; i += TD)                       // 64*128/4 float4
            ((float4*)&sW[0][0])[i] = ((const float4*)W)[kc * 32 + i];
        for (int i = t; i < 512; i += TD) {                      // 32 rows * 16 quads
            int r = i >> 4, kq = i & 15;
            int gr = row0 + r;
            float4 v = (gr < n) ? ((const float4*)x)[gr * 32 + (kc >> 2) + kq]
                                : make_float4(0.f, 0.f, 0.f, 0.f);
            sX[kq * 4 + 0][r] = v.x; sX[kq * 4 + 1][r] = v.y;
            sX[kq * 4 + 2][r] = v.z; sX[kq * 4 + 3][r] = v.w;
        }
        __syncthreads();
        #pragma unroll
        for (int k = 0; k < 64; k++) {
            float4 a = *(const float4*)&sX[k][rt * 4];
            float4 b = *(const float4*)&sW[k][ct * 4];
            acc[0][0] += a.x * b.x; acc[0][1] += a.x * b.y; acc[0][2] += a.x * b.z; acc[0][3] += a.x * b.w;
            acc[1][0] += a.y * b.x; acc[1][1] += a.y * b.y; acc[1][2] += a.y * b.z; acc[1][3] += a.y * b.w;
            acc[2][0] += a.z * b.x; acc[2][1] += a.z * b.y; acc[2][2] += a.z * b.z; acc[2][3] += a.z * b.w;
            acc[3][0] += a.w * b.x; acc[3][1] += a.w * b.y; acc[3][2] += a.w * b.z; acc[3][3] += a.w * b.w;
        }
        __syncthreads();
    }
    for (int i = 0; i < 4; i++) {
        int gr = row0 + rt * 4 + i;
        if (gr < n) {
            float dv = dinv[gr];
            float4 o;
            o.x = acc[i][0] * dv; o.y = acc[i][1] * dv;
            o.z = acc[i][2] * dv; o.w = acc[i][3] * dv;
            ((float4*)xws)[gr * 32 + ct] = o;
        }
    }
}

// ---------------- aggregation: one wave per node ----------------
// agg = dinv[d] * (xws[d] + sum_{s in in(d)} xws[s]); h0 = relu(agg+bg) + x
__global__ __launch_bounds__(256) void k_agg(const float* __restrict__ xws,
                                             const float* __restrict__ x,
                                             const int* __restrict__ rowStart,
                                             const int* __restrict__ deg,
                                             const int* __restrict__ csr,
                                             const float* __restrict__ dinv,
                                             const float* __restrict__ bg,
                                             float* __restrict__ h0, int n) {
    int wave = threadIdx.x >> 6;
    int lane = threadIdx.x & 63;
    int node = blockIdx.x * 4 + wave;
    if (node >= n) return;
    const float2* xws2 = (const float2*)xws;
    float2 acc = xws2[(size_t)node * 64 + lane];    // self-loop term
    int st = rowStart[node];
    int cnt = deg[node];
    for (int i = 0; i < cnt; i++) {
        int s = csr[st + i];
        float2 v = xws2[(size_t)s * 64 + lane];
        acc.x += v.x; acc.y += v.y;
    }
    float dv = dinv[node];
    float2 b = ((const float2*)bg)[lane];
    float2 xv = ((const float2*)x)[(size_t)node * 64 + lane];
    float2 o;
    o.x = fmaxf(acc.x * dv + b.x, 0.f) + xv.x;
    o.y = fmaxf(acc.y * dv + b.y, 0.f) + xv.y;
    ((float2*)h0)[(size_t)node * 64 + lane] = o;
}

// ---------------- fused MLP: 16 rows per block ----------------
// h1 = relu(h0@W1+b1) [16x128]; h2 = relu(h1@W2+b2) [16x64]; out = h2@W3+b3 [16x2]
__global__ __launch_bounds__(256) void k_mlp(const float* __restrict__ h0,
                                             const float* __restrict__ W1, const float* __restrict__ b1,
                                             const float* __restrict__ W2, const float* __restrict__ b2,
                                             const float* __restrict__ W3, const float* __restrict__ b3,
                                             float* __restrict__ out, int n) {
    __shared__ float sW[64][128];   // 32KB: W1 k-chunks, then W2 (128x64) flat
    __shared__ float sh0[128][16];  // 8KB  [k][r]
    __shared__ float sh1[128][16];  // 8KB  [k][r]
    __shared__ float sh2[64][16];   // 4KB  [k][r]
    __shared__ float sW3[128];      // 64x2
    __shared__ float sb1[128];
    __shared__ float sb2[64];
    __shared__ float sb3[2];
    int t = threadIdx.x;
    int row0 = blockIdx.x * 16;

    // stage h0 tile transposed: 16 rows x 32 quads = 512 float4
    for (int i = t; i < 512; i += TD) {
        int r = i >> 5, kq = i & 31;
        int gr = row0 + r;
        float4 v = (gr < n) ? ((const float4*)h0)[gr * 32 + kq]
                            : make_float4(0.f, 0.f, 0.f, 0.f);
        sh0[kq * 4 + 0][r] = v.x; sh0[kq * 4 + 1][r] = v.y;
        sh0[kq * 4 + 2][r] = v.z; sh0[kq * 4 + 3][r] = v.w;
    }
    if (t < 128) sW3[t] = W3[t];
    if (t < 128) sb1[t] = b1[t];
    if (t < 64)  sb2[t] = b2[t];
    if (t < 2)   sb3[t] = b3[t];

    // ---- stage 1: 16 rows x 128 cols; rt=t>>6 (4 rows each), ct=t&63 (2 cols each)
    int rt = t >> 6;   // 0..3
    int ct = t & 63;   // 0..63
    float acc1[4][2] = {};
    for (int kc = 0; kc < 128; kc += 64) {
        for (int i = t; i < 2048; i += TD)
            ((float4*)&sW[0][0])[i] = ((const float4*)W1)[kc * 32 + i];
        __syncthreads();   // also covers sh0/bias staging on first iter
        #pragma unroll
        for (int kk = 0; kk < 64; kk++) {
            int k = kc + kk;
            float4 a = *(const float4*)&sh0[k][rt * 4];
            float2 b = *(const float2*)&sW[kk][ct * 2];
            acc1[0][0] += a.x * b.x; acc1[0][1] += a.x * b.y;
            acc1[1][0] += a.y * b.x; acc1[1][1] += a.y * b.y;
            acc1[2][0] += a.z * b.x; acc1[2][1] += a.z * b.y;
            acc1[3][0] += a.w * b.x; acc1[3][1] += a.w * b.y;
        }
        __syncthreads();
    }
    #pragma unroll
    for (int j = 0; j < 2; j++) {
        float bb = sb1[ct * 2 + j];
        #pragma unroll
        for (int i = 0; i < 4; i++)
            sh1[ct * 2 + j][rt * 4 + i] = fmaxf(acc1[i][j] + bb, 0.f);
    }
    __syncthreads();

    // ---- stage 2: 16 rows x 64 cols; W2 (128x64) flat into sW
    for (int i = t; i < 2048; i += TD)
        ((float4*)&sW[0][0])[i] = ((const float4*)W2)[i];
    __syncthreads();
    {
        const float* sW2f = &sW[0][0];
        float acc2[4] = {};
        int c = t & 63;       // one col each
        int r4 = (t >> 6) * 4;
        #pragma unroll
        for (int k = 0; k < 128; k++) {
            float4 a = *(const float4*)&sh1[k][r4];
            float b = sW2f[k * 64 + c];
            acc2[0] += a.x * b; acc2[1] += a.y * b; acc2[2] += a.z * b; acc2[3] += a.w * b;
        }
        float bb = sb2[c];
        #pragma unroll
        for (int i = 0; i < 4; i++)
            sh2[c][r4 + i] = fmaxf(acc2[i] + bb, 0.f);
    }
    __syncthreads();

    // ---- stage 3: 16 rows x 2 cols = 32 outputs
    if (t < 32) {
        int r = t >> 1, c = t & 1;
        float acc = sb3[c];
        #pragma unroll
        for (int k = 0; k < 64; k++)
            acc += sh2[k][r] * sW3[k * 2 + c];
        int gr = row0 + r;
        if (gr < n) out[(size_t)c * n + gr] = acc;
    }
}

// ---------------- host launcher ----------------

extern "C" void kernel_launch(void* const* d_in, const int* in_sizes, int n_in,
                              void* d_out, int out_size, void* d_ws, size_t ws_size,
                              hipStream_t stream) {
    const float* x  = (const float*)d_in[0];
    const int*   ei = (const int*)d_in[1];
    const float* Wg = (const float*)d_in[2];
    const float* bg = (const float*)d_in[3];
    const float* W1 = (const float*)d_in[4];
    const float* b1 = (const float*)d_in[5];
    const float* W2 = (const float*)d_in[6];
    const float* b2 = (const float*)d_in[7];
    const float* W3 = (const float*)d_in[8];
    const float* b3 = (const float*)d_in[9];
    float* out = (float*)d_out;

    int n = in_sizes[0] / 128;
    int e = in_sizes[1] / 2;
    const int* src = ei;
    const int* dst = ei + e;

    // workspace carve-up (256B aligned)
    char* ws = (char*)d_ws;
    size_t off = 0;
    auto alloc = [&](size_t bytes) -> void* {
        void* p = ws + off;
        off = (off + bytes + 255) & ~(size_t)255;
        return p;
    };
    int*   deg      = (int*)alloc(sizeof(int) * (size_t)n);
    int*   rowStart = (int*)alloc(sizeof(int) * (size_t)n);
    int*   cursor   = (int*)alloc(sizeof(int) * (size_t)n);
    float* dinv     = (float*)alloc(sizeof(float) * (size_t)n);
    int*   bsum     = (int*)alloc(sizeof(int) * 1024);
    int*   csr      = (int*)alloc(sizeof(int) * (size_t)e);
    float* xws      = (float*)alloc(sizeof(float) * (size_t)n * 128);
    float* h0       = (float*)alloc(sizeof(float) * (size_t)n * 128);
    (void)ws_size; (void)n_in; (void)out_size;

    int nb = (n + TD - 1) / TD;      // 196 for n=50000 (must be <= 256 for k_scanB)
    int eb = (e + TD - 1) / TD;

    hipLaunchKernelGGL(k_init_deg, dim3(nb), dim3(TD), 0, stream, deg, n);
    hipLaunchKernelGGL(k_count,    dim3(eb), dim3(TD), 0, stream, dst, e, deg);
    hipLaunchKernelGGL(k_scanA,    dim3(nb), dim3(TD), 0, stream, deg, n, bsum);
    hipLaunchKernelGGL(k_scanB,    dim3(1),  dim3(TD), 0, stream, bsum, nb);
    hipLaunchKernelGGL(k_scanC,    dim3(nb), dim3(TD), 0, stream, deg, n, bsum, rowStart, cursor, dinv);
    hipLaunchKernelGGL(k_fill,     dim3(eb), dim3(TD), 0, stream, src, dst, e, cursor, csr);
    hipLaunchKernelGGL(k_xw,       dim3((n + 31) / 32), dim3(TD), 0, stream, x, Wg, dinv, xws, n);
    hipLaunchKernelGGL(k_agg,      dim3((n + 3) / 4),   dim3(TD), 0, stream, xws, x, rowStart, deg, csr, dinv, bg, h0, n);
    hipLaunchKernelGGL(k_mlp,      dim3((n + 15) / 16), dim3(TD), 0, stream, h0, W1, b1, W2, b2, W3, b3, out, n);
}

// Round 2
// 335.947 us; speedup vs baseline: 1.1326x; 1.1326x over previous
//
#include <hip/hip_runtime.h>

#define TD 256   // threads per block everywhere

// ---------------- degree / CSR build ----------------

__global__ void k_init_deg(int* __restrict__ deg, int n) {
    int i = blockIdx.x * TD + threadIdx.x;
    if (i < n) deg[i] = 0;
}

__global__ void k_count(const int* __restrict__ dst, int e, int* __restrict__ deg) {
    int i = blockIdx.x * TD + threadIdx.x;
    if (i < e) atomicAdd(&deg[dst[i]], 1);
}

// per-block sums of deg
__global__ void k_scanA(const int* __restrict__ deg, int n, int* __restrict__ bsum) {
    __shared__ int s[TD];
    int t = threadIdx.x;
    int i = blockIdx.x * TD + t;
    s[t] = (i < n) ? deg[i] : 0;
    __syncthreads();
    for (int off = TD / 2; off > 0; off >>= 1) {
        if (t < off) s[t] += s[t + off];
        __syncthreads();
    }
    if (t == 0) bsum[blockIdx.x] = s[0];
}

// exclusive scan of block sums (nb <= 256), in place
__global__ void k_scanB(int* __restrict__ bsum, int nb) {
    __shared__ int s[TD];
    int t = threadIdx.x;
    int v = (t < nb) ? bsum[t] : 0;
    s[t] = v;
    __syncthreads();
    for (int off = 1; off < TD; off <<= 1) {
        int u = (t >= off) ? s[t - off] : 0;
        __syncthreads();
        s[t] += u;
        __syncthreads();
    }
    if (t < nb) bsum[t] = s[t] - v;   // exclusive
}

// per-block exclusive scan + block offset -> rowStart, cursor; also dinv = rsqrt(deg+1)
__global__ void k_scanC(const int* __restrict__ deg, int n, const int* __restrict__ bsum,
                        int* __restrict__ rowStart, int* __restrict__ cursor,
                        float* __restrict__ dinv) {
    __shared__ int s[TD];
    int t = threadIdx.x;
    int i = blockIdx.x * TD + t;
    int v = (i < n) ? deg[i] : 0;
    s[t] = v;
    __syncthreads();
    for (int off = 1; off < TD; off <<= 1) {
        int u = (t >= off) ? s[t - off] : 0;
        __syncthreads();
        s[t] += u;
        __syncthreads();
    }
    if (i < n) {
        int rs = bsum[blockIdx.x] + s[t] - v;
        rowStart[i] = rs;
        cursor[i]   = rs;
        dinv[i]     = rsqrtf((float)(v + 1));   // +1 self-loop
    }
}

__global__ void k_fill(const int* __restrict__ src, const int* __restrict__ dst, int e,
                       int* __restrict__ cursor, int* __restrict__ csr) {
    int i = blockIdx.x * TD + threadIdx.x;
    if (i < e) {
        int d = dst[i];
        int slot = atomicAdd(&cursor[d], 1);
        csr[slot] = src[i];
    }
}

// FMA micro-tile helper: acc[I][0..3] += a.{x,y,z,w} dotted against b0..b3 rows
#define FMA4(ACC, A, B0, B1, B2, B3)                                      \
    ACC[0] += A.x * B0.x + A.y * B1.x + A.z * B2.x + A.w * B3.x;          \
    ACC[1] += A.x * B0.y + A.y * B1.y + A.z * B2.y + A.w * B3.y;          \
    ACC[2] += A.x * B0.z + A.y * B1.z + A.z * B2.z + A.w * B3.z;          \
    ACC[3] += A.x * B0.w + A.y * B1.w + A.z * B2.w + A.w * B3.w;

// ---------------- xws = (x @ Wg) * dinv[row] ----------------
// 32 rows x 128 cols per block. sX in natural [row][col] layout (pad +4):
// A-reads are wave-uniform broadcasts, staging stores are dense b128 -> no conflicts.
__global__ __launch_bounds__(256) void k_xw(const float* __restrict__ x,
                                            const float* __restrict__ W,
                                            const float* __restrict__ dinv,
                                            float* __restrict__ xws, int n) {
    __shared__ float sX[32][132];   // [r][k], 16.9 KB
    __shared__ float sW[64 * 128];  // [k][c] chunk, 32 KB
    int t = threadIdx.x;
    int row0 = blockIdx.x * 32;
    int rt = t >> 5;   // 0..7 -> rows rt*4..+3
    int ct = t & 31;   // 0..31 -> cols ct*4..+3
    float acc[4][4] = {};

    // stage X tile once: 32 rows x 32 quads, natural layout
    for (int i = t; i < 1024; i += TD) {
        int r = i >> 5, kq = i & 31;
        int gr = row0 + r;
        float4 v = (gr < n) ? ((const float4*)x)[(size_t)gr * 32 + kq]
                            : make_float4(0.f, 0.f, 0.f, 0.f);
        *(float4*)&sX[r][kq * 4] = v;
    }

    for (int kc = 0; kc < 128; kc += 64) {
        __syncthreads();   // protect sW (and cover sX staging on first iter)
        for (int i = t; i < 2048; i += TD)
            ((float4*)sW)[i] = ((const float4*)W)[kc * 32 + i];
        __syncthreads();
        #pragma unroll
        for (int k4 = 0; k4 < 64; k4 += 4) {
            float4 a0 = *(const float4*)&sX[rt * 4 + 0][kc + k4];
            float4 a1 = *(const float4*)&sX[rt * 4 + 1][kc + k4];
            float4 a2 = *(const float4*)&sX[rt * 4 + 2][kc + k4];
            float4 a3 = *(const float4*)&sX[rt * 4 + 3][kc + k4];
            float4 b0 = *(const float4*)&sW[(k4 + 0) * 128 + ct * 4];
            float4 b1 = *(const float4*)&sW[(k4 + 1) * 128 + ct * 4];
            float4 b2 = *(const float4*)&sW[(k4 + 2) * 128 + ct * 4];
            float4 b3 = *(const float4*)&sW[(k4 + 3) * 128 + ct * 4];
            FMA4(acc[0], a0, b0, b1, b2, b3);
            FMA4(acc[1], a1, b0, b1, b2, b3);
            FMA4(acc[2], a2, b0, b1, b2, b3);
            FMA4(acc[3], a3, b0, b1, b2, b3);
        }
    }
    #pragma unroll
    for (int i = 0; i < 4; i++) {
        int gr = row0 + rt * 4 + i;
        if (gr < n) {
            float dv = dinv[gr];
            float4 o;
            o.x = acc[i][0] * dv; o.y = acc[i][1] * dv;
            o.z = acc[i][2] * dv; o.w = acc[i][3] * dv;
            ((float4*)xws)[(size_t)gr * 32 + ct] = o;
        }
    }
}

// ---------------- aggregation: one wave per node, 4-way unrolled ----------------
// agg = dinv[d] * (xws[d] + sum_{s in in(d)} xws[s]); h0 = relu(agg+bg) + x
__global__ __launch_bounds__(256) void k_agg(const float* __restrict__ xws,
                                             const float* __restrict__ x,
                                             const int* __restrict__ rowStart,
                                             const int* __restrict__ deg,
                                             const int* __restrict__ csr,
                                             const float* __restrict__ dinv,
                                             const float* __restrict__ bg,
                                             float* __restrict__ h0, int n) {
    int wave = threadIdx.x >> 6;
    int lane = threadIdx.x & 63;
    int node = blockIdx.x * 4 + wave;
    if (node >= n) return;
    const float2* xws2 = (const float2*)xws;
    float2 a0 = xws2[(size_t)node * 64 + lane];    // self-loop term
    float2 a1 = {0.f, 0.f}, a2 = {0.f, 0.f}, a3 = {0.f, 0.f};
    int st = rowStart[node];
    int cnt = deg[node];
    int i = 0;
    for (; i + 4 <= cnt; i += 4) {
        int s0 = csr[st + i + 0];
        int s1 = csr[st + i + 1];
        int s2 = csr[st + i + 2];
        int s3 = csr[st + i + 3];
        float2 v0 = xws2[(size_t)s0 * 64 + lane];
        float2 v1 = xws2[(size_t)s1 * 64 + lane];
        float2 v2 = xws2[(size_t)s2 * 64 + lane];
        float2 v3 = xws2[(size_t)s3 * 64 + lane];
        a0.x += v0.x; a0.y += v0.y;
        a1.x += v1.x; a1.y += v1.y;
        a2.x += v2.x; a2.y += v2.y;
        a3.x += v3.x; a3.y += v3.y;
    }
    for (; i < cnt; i++) {
        int s = csr[st + i];
        float2 v = xws2[(size_t)s * 64 + lane];
        a0.x += v.x; a0.y += v.y;
    }
    float2 acc;
    acc.x = (a0.x + a1.x) + (a2.x + a3.x);
    acc.y = (a0.y + a1.y) + (a2.y + a3.y);
    float dv = dinv[node];
    float2 b = ((const float2*)bg)[lane];
    float2 xv = ((const float2*)x)[(size_t)node * 64 + lane];
    float2 o;
    o.x = fmaxf(acc.x * dv + b.x, 0.f) + xv.x;
    o.y = fmaxf(acc.y * dv + b.y, 0.f) + xv.y;
    ((float2*)h0)[(size_t)node * 64 + lane] = o;
}

// ---------------- fused MLP: 32 rows per block, natural layouts ----------------
// h1 = relu(h0@W1+b1) [32x128]; h2 = relu(h1@W2+b2) [32x64]; out = h2@W3+b3 [32x2]
__global__ __launch_bounds__(256) void k_mlp(const float* __restrict__ h0g,
                                             const float* __restrict__ W1, const float* __restrict__ b1,
                                             const float* __restrict__ W2, const float* __restrict__ b2,
                                             const float* __restrict__ W3, const float* __restrict__ b3,
                                             float* __restrict__ out, int n) {
    __shared__ float sh0[32][132];  // 16.9 KB, [r][k]; overlaid by sh2t after stage 1
    __shared__ float sW[32 * 128];  // 16 KB weight chunk (W1 k-chunks, then W2 halves)
    __shared__ float sh1[32][132];  // 16.9 KB, [r][k]
    float* sh2t = &sh0[0][0];       // overlay: [64][36] = 2304 floats <= 4224 avail
    int t = threadIdx.x;
    int row0 = blockIdx.x * 32;

    // stage h0 tile: 32 rows x 32 quads, natural layout (dense b128 stores)
    for (int i = t; i < 1024; i += TD) {
        int r = i >> 5, kq = i & 31;
        int gr = row0 + r;
        float4 v = (gr < n) ? ((const float4*)h0g)[(size_t)gr * 32 + kq]
                            : make_float4(0.f, 0.f, 0.f, 0.f);
        *(float4*)&sh0[r][kq * 4] = v;
    }

    // ---- stage 1: [32x128] @ W1[128x128]; rt rows, ct cols, 4x4 per thread
    int rt = t >> 5;   // 0..7
    int ct = t & 31;   // 0..31
    float acc1[4][4] = {};
    for (int kc = 0; kc < 128; kc += 32) {
        __syncthreads();   // protect sW restage; first iter also covers sh0 staging
        for (int i = t; i < 1024; i += TD)
            ((float4*)sW)[i] = ((const float4*)W1)[kc * 32 + i];
        __syncthreads();
        #pragma unroll
        for (int k4 = 0; k4 < 32; k4 += 4) {
            float4 a0 = *(const float4*)&sh0[rt * 4 + 0][kc + k4];
            float4 a1 = *(const float4*)&sh0[rt * 4 + 1][kc + k4];
            float4 a2 = *(const float4*)&sh0[rt * 4 + 2][kc + k4];
            float4 a3 = *(const float4*)&sh0[rt * 4 + 3][kc + k4];
            float4 w0 = *(const float4*)&sW[(k4 + 0) * 128 + ct * 4];
            float4 w1 = *(const float4*)&sW[(k4 + 1) * 128 + ct * 4];
            float4 w2 = *(const float4*)&sW[(k4 + 2) * 128 + ct * 4];
            float4 w3 = *(const float4*)&sW[(k4 + 3) * 128 + ct * 4];
            FMA4(acc1[0], a0, w0, w1, w2, w3);
            FMA4(acc1[1], a1, w0, w1, w2, w3);
            FMA4(acc1[2], a2, w0, w1, w2, w3);
            FMA4(acc1[3], a3, w0, w1, w2, w3);
        }
    }
    {
        float4 bb = *(const float4*)&b1[ct * 4];
        #pragma unroll
        for (int i = 0; i < 4; i++) {
            float4 o;
            o.x = fmaxf(acc1[i][0] + bb.x, 0.f);
            o.y = fmaxf(acc1[i][1] + bb.y, 0.f);
            o.z = fmaxf(acc1[i][2] + bb.z, 0.f);
            o.w = fmaxf(acc1[i][3] + bb.w, 0.f);
            *(float4*)&sh1[rt * 4 + i][ct * 4] = o;   // dense b128 store
        }
    }

    // ---- stage 2: [32x128] @ W2[128x64]; 2 rows x 4 cols per thread
    int rt2 = t >> 4;  // 0..15 -> rows rt2*2..+1
    int ct2 = t & 15;  // 0..15 -> cols ct2*4..+3
    float acc2[2][4] = {};
    for (int c = 0; c < 2; c++) {       // K halves of 64
        __syncthreads();   // sh1 writes visible; sW free to restage
        for (int i = t; i < 1024; i += TD)
            ((float4*)sW)[i] = ((const float4*)W2)[c * 1024 + i];   // [64][64]
        __syncthreads();
        #pragma unroll
        for (int k4 = 0; k4 < 64; k4 += 4) {
            float4 a0 = *(const float4*)&sh1[rt2 * 2 + 0][c * 64 + k4];
            float4 a1 = *(const float4*)&sh1[rt2 * 2 + 1][c * 64 + k4];
            float4 w0 = *(const float4*)&sW[(k4 + 0) * 64 + ct2 * 4];
            float4 w1 = *(const float4*)&sW[(k4 + 1) * 64 + ct2 * 4];
            float4 w2 = *(const float4*)&sW[(k4 + 2) * 64 + ct2 * 4];
            float4 w3 = *(const float4*)&sW[(k4 + 3) * 64 + ct2 * 4];
            FMA4(acc2[0], a0, w0, w1, w2, w3);
            FMA4(acc2[1], a1, w0, w1, w2, w3);
        }
    }
    {
        float4 bb = *(const float4*)&b2[ct2 * 4];
        __syncthreads();   // all stage-2 reads of sh1/sW done (sh2t overlays sh0, long dead)
        #pragma unroll
        for (int i = 0; i < 2; i++) {
            int r = rt2 * 2 + i;
            sh2t[(ct2 * 4 + 0) * 36 + r] = fmaxf(acc2[i][0] + bb.x, 0.f);
            sh2t[(ct2 * 4 + 1) * 36 + r] = fmaxf(acc2[i][1] + bb.y, 0.f);
            sh2t[(ct2 * 4 + 2) * 36 + r] = fmaxf(acc2[i][2] + bb.z, 0.f);
            sh2t[(ct2 * 4 + 3) * 36 + r] = fmaxf(acc2[i][3] + bb.w, 0.f);
        }
    }
    __syncthreads();

    // ---- stage 3: 32 rows x 2 cols; sh2t[k][r] reads are stride-1 across lanes
    if (t < 64) {
        int r = t >> 1, c = t & 1;
        float acc = b3[c];
        #pragma unroll
        for (int k = 0; k < 64; k++)
            acc += sh2t[k * 36 + r] * W3[k * 2 + c];
        int gr = row0 + r;
        if (gr < n) out[(size_t)c * n + gr] = acc;
    }
}

// ---------------- host launcher ----------------

extern "C" void kernel_launch(void* const* d_in, const int* in_sizes, int n_in,
                              void* d_out, int out_size, void* d_ws, size_t ws_size,
                              hipStream_t stream) {
    const float* x  = (const float*)d_in[0];
    const int*   ei = (const int*)d_in[1];
    const float* Wg = (const float*)d_in[2];
    const float* bg = (const float*)d_in[3];
    const float* W1 = (const float*)d_in[4];
    const float* b1 = (const float*)d_in[5];
    const float* W2 = (const float*)d_in[6];
    const float* b2 = (const float*)d_in[7];
    const float* W3 = (const float*)d_in[8];
    const float* b3 = (const float*)d_in[9];
    float* out = (float*)d_out;

    int n = in_sizes[0] / 128;
    int e = in_sizes[1] / 2;
    const int* src = ei;
    const int* dst = ei + e;

    // workspace carve-up (256B aligned)
    char* ws = (char*)d_ws;
    size_t off = 0;
    auto alloc = [&](size_t bytes) -> void* {
        void* p = ws + off;
        off = (off + bytes + 255) & ~(size_t)255;
        return p;
    };
    int*   deg      = (int*)alloc(sizeof(int) * (size_t)n);
    int*   rowStart = (int*)alloc(sizeof(int) * (size_t)n);
    int*   cursor   = (int*)alloc(sizeof(int) * (size_t)n);
    float* dinv     = (float*)alloc(sizeof(float) * (size_t)n);
    int*   bsum     = (int*)alloc(sizeof(int) * 1024);
    int*   csr      = (int*)alloc(sizeof(int) * (size_t)e);
    float* xws      = (float*)alloc(sizeof(float) * (size_t)n * 128);
    float* h0       = (float*)alloc(sizeof(float) * (size_t)n * 128);
    (void)ws_size; (void)n_in; (void)out_size;

    int nb = (n + TD - 1) / TD;      // 196 for n=50000 (must be <= 256 for k_scanB)
    int eb = (e + TD - 1) / TD;

    hipLaunchKernelGGL(k_init_deg, dim3(nb), dim3(TD), 0, stream, deg, n);
    hipLaunchKernelGGL(k_count,    dim3(eb), dim3(TD), 0, stream, dst, e, deg);
    hipLaunchKernelGGL(k_scanA,    dim3(nb), dim3(TD), 0, stream, deg, n, bsum);
    hipLaunchKernelGGL(k_scanB,    dim3(1),  dim3(TD), 0, stream, bsum, nb);
    hipLaunchKernelGGL(k_scanC,    dim3(nb), dim3(TD), 0, stream, deg, n, bsum, rowStart, cursor, dinv);
    hipLaunchKernelGGL(k_fill,     dim3(eb), dim3(TD), 0, stream, src, dst, e, cursor, csr);
    hipLaunchKernelGGL(k_xw,       dim3((n + 31) / 32), dim3(TD), 0, stream, x, Wg, dinv, xws, n);
    hipLaunchKernelGGL(k_agg,      dim3((n + 3) / 4),   dim3(TD), 0, stream, xws, x, rowStart, deg, csr, dinv, bg, h0, n);
    hipLaunchKernelGGL(k_mlp,      dim3((n + 31) / 32), dim3(TD), 0, stream, h0, W1, b1, W2, b2, W3, b3, out, n);
}